// Round 3
// baseline (1402.090 us; speedup 1.0000x reference)
//
#include <hip/hip_runtime.h>
#include <stdint.h>

#define B 64
#define T 100
#define IN_F 700
#define RED 256
#define WID 4096
#define CLS 20
#define BT (B*T)                   // 6400
#define NELEM (BT*WID)             // 26,214,400
#define LOGITS_OFF 0
#define SPIKES_OFF (B*CLS)         // 1280
#define DRIVE_OFF (SPIKES_OFF + NELEM)

// workspace layout in 4-byte units
#define WS_SLOTS 0                            // 3 u32 (abs-max bits)
#define WS_WSQ 16                             // 256*700 quantized spatial_W
#define WS_W1Q (WS_WSQ + RED*IN_F)            // 4096*256 quantized fc1_W
#define WS_W2Q (WS_W1Q + WID*RED)             // 20*4096 quantized fc2_W
#define WS_XP  (WS_W2Q + CLS*WID)             // 6400*256 spatial act
#define WS_CO  (WS_XP + BT*RED)               // 6400*256 conv act
#define WS_WEIGHTED (WS_CO + BT*RED)          // 64*4096

__host__ __device__ __forceinline__ uint32_t rotl32(uint32_t v, int r) {
  return (v << r) | (v >> (32 - r));
}

// JAX threefry2x32 (20 rounds), bit-exact.
__host__ __device__ __forceinline__ void threefry2x32(uint32_t k0, uint32_t k1,
                                                      uint32_t x0, uint32_t x1,
                                                      uint32_t& o0, uint32_t& o1) {
  uint32_t k2 = k0 ^ k1 ^ 0x1BD11BDAu;
  x0 += k0; x1 += k1;
#define TF_R(r) { x0 += x1; x1 = rotl32(x1, (r)); x1 ^= x0; }
  TF_R(13) TF_R(15) TF_R(26) TF_R(6)
  x0 += k1; x1 += k2 + 1u;
  TF_R(17) TF_R(29) TF_R(16) TF_R(24)
  x0 += k2; x1 += k0 + 2u;
  TF_R(13) TF_R(15) TF_R(26) TF_R(6)
  x0 += k0; x1 += k1 + 3u;
  TF_R(17) TF_R(29) TF_R(16) TF_R(24)
  x0 += k1; x1 += k2 + 4u;
  TF_R(13) TF_R(15) TF_R(26) TF_R(6)
  x0 += k2; x1 += k0 + 5u;
#undef TF_R
  o0 = x0; o1 = x1;
}

__global__ void absmax_kernel(const float* __restrict__ w, int n, uint32_t* slot) {
  __shared__ uint32_t sm[256];
  uint32_t m = 0u;
  for (int i = blockIdx.x * 256 + threadIdx.x; i < n; i += gridDim.x * 256)
    m = max(m, __float_as_uint(fabsf(w[i])));
  sm[threadIdx.x] = m;
  __syncthreads();
  for (int s = 128; s > 0; s >>= 1) {
    if (threadIdx.x < s) sm[threadIdx.x] = max(sm[threadIdx.x], sm[threadIdx.x + s]);
    __syncthreads();
  }
  if (threadIdx.x == 0) atomicMax(slot, sm[0]);
}

// q4: scale = max(absmax/7, 1e-8); q = rintf(w/scale)*scale  (all CR ops, matches jnp)
__global__ void quant_kernel(const float* __restrict__ w, float* __restrict__ q,
                             int n, const uint32_t* __restrict__ slot) {
  float s = fmaxf(__uint_as_float(*slot) / 7.0f, 1e-8f);
  int i = blockIdx.x * 256 + threadIdx.x;
  if (i < n) q[i] = rintf(w[i] / s) * s;
}

// xp[bt,r] = relu(sum_f x[bt,f]*Wsq[r,f] + sb[r])
// strict sequential-f fma chain from 0 — matches Eigen gebp per-element order.
__global__ void __launch_bounds__(256) spatial_kernel(const float* __restrict__ x,
                                                      const float* __restrict__ wq,
                                                      const float* __restrict__ bias,
                                                      float* __restrict__ xp) {
  __shared__ float xs[8 * IN_F];
  int bt0 = blockIdx.x * 8;
  const float* xrow = x + (size_t)bt0 * IN_F;
  for (int i = threadIdx.x; i < 8 * IN_F; i += 256) xs[i] = xrow[i];
  __syncthreads();
  int r = threadIdx.x;
  const float* wr = wq + (size_t)r * IN_F;
  float acc[8] = {0.f,0.f,0.f,0.f,0.f,0.f,0.f,0.f};
  for (int f = 0; f < IN_F; ++f) {
    float wv = wr[f];
#pragma unroll
    for (int j = 0; j < 8; ++j) acc[j] = fmaf(xs[j * IN_F + f], wv, acc[j]);
  }
  float bv = bias[r];
#pragma unroll
  for (int j = 0; j < 8; ++j)
    xp[(size_t)(bt0 + j) * RED + r] = fmaxf(acc[j] + bv, 0.0f);
}

// co[b,t,o] = relu(sum_{h=0..4} sum_{ic} xp[b,t+h-2,ic]*Wc[o,ic,h] + cb[o])
// h outer / ic inner (NHWC patch order: channels fastest), zero pad.
__global__ void __launch_bounds__(256) conv_kernel(const float* __restrict__ xp,
                                                   const float* __restrict__ wc,
                                                   const float* __restrict__ bias,
                                                   float* __restrict__ co) {
  __shared__ float xr[14 * RED];
  int b = blockIdx.x / 10;
  int t0 = (blockIdx.x % 10) * 10;
  for (int i = threadIdx.x; i < 14 * RED; i += 256) {
    int row = i >> 8, c = i & 255;
    int t = t0 + row - 2;
    xr[i] = (t >= 0 && t < T) ? xp[((size_t)b * T + t) * RED + c] : 0.0f;
  }
  __syncthreads();
  int o = threadIdx.x;
  const float* w0 = wc + (size_t)o * (RED * 5);
  float acc[10] = {0.f,0.f,0.f,0.f,0.f,0.f,0.f,0.f,0.f,0.f};
  for (int h = 0; h < 5; ++h) {
    for (int ic = 0; ic < RED; ++ic) {
      float wv = w0[ic * 5 + h];
#pragma unroll
      for (int j = 0; j < 10; ++j)
        acc[j] = fmaf(xr[(j + h) * RED + ic], wv, acc[j]);
    }
  }
  float bv = bias[o];
  for (int j = 0; j < 10; ++j)
    co[((size_t)b * T + t0 + j) * RED + o] = fmaxf(acc[j] + bv, 0.0f);
}

// drive[bt,w] = softplus(sum_r co[bt,r]*W1q[w,r] + b1[w]) * latent[t] * |gain|
// softplus = logaddexp(v,0) = max(v,0) + log1p(exp(-|v|))  (true log1p)
__global__ void __launch_bounds__(256) fc1_kernel(const float* __restrict__ co,
                                                  const float* __restrict__ w1,
                                                  const float* __restrict__ bias,
                                                  const float* __restrict__ latent,
                                                  const float* __restrict__ gain,
                                                  float* __restrict__ out) {
  __shared__ float cs[8 * RED];
  int bt0 = (blockIdx.x >> 4) * 8;
  int wc = blockIdx.x & 15;
  for (int i = threadIdx.x; i < 8 * RED; i += 256) cs[i] = co[(size_t)bt0 * RED + i];
  __syncthreads();
  int w = wc * 256 + threadIdx.x;
  const float* wr = w1 + (size_t)w * RED;
  float acc[8] = {0.f,0.f,0.f,0.f,0.f,0.f,0.f,0.f};
  for (int r = 0; r < RED; ++r) {
    float wv = wr[r];
#pragma unroll
    for (int j = 0; j < 8; ++j) acc[j] = fmaf(cs[j * RED + r], wv, acc[j]);
  }
  float bv = bias[w];
  float g = fabsf(gain[0]);
  for (int j = 0; j < 8; ++j) {
    float v = acc[j] + bv;
    float e = expf(-fabsf(v));
    float l = log1pf(e);
    float sp = fmaxf(v, 0.0f) + l;
    int bt = bt0 + j;
    int t = bt % T;
    float d = (sp * latent[t]) * g;
    out[DRIVE_OFF + (size_t)bt * WID + w] = d;
  }
}

// spikes = min(pois,1) = [lam>0 && log(u1) > -lam].
// u1: partitionable threefry random_bits — element p's block is (0,p) under the
// FIRST loop subkey; 32-bit bits = XOR of the two output words.
__global__ void __launch_bounds__(256) spike_kernel(float* __restrict__ out,
                                                    uint32_t k0, uint32_t k1) {
  uint32_t p = blockIdx.x * 256u + threadIdx.x;
  float lam = out[DRIVE_OFF + p];
  uint32_t y0, y1;
  threefry2x32(k0, k1, 0u, p, y0, y1);
  uint32_t bits = y0 ^ y1;
  float u = __uint_as_float((bits >> 9) | 0x3f800000u) - 1.0f;
  float s = (lam > 0.0f && logf(u) > -lam) ? 1.0f : 0.0f;
  out[SPIKES_OFF + p] = s;
}

// weighted[b,w] = sum_t spikes[b,t,w]*decay[t], t sequential
__global__ void __launch_bounds__(256) weighted_kernel(const float* __restrict__ out,
                                                       float* __restrict__ wt) {
  __shared__ float dec[128];
  if (threadIdx.x < T) {
    float step = 2.0f / 99.0f;
    float a = step * (float)threadIdx.x;
    dec[threadIdx.x] = expf(a - 2.0f);
  }
  __syncthreads();
  int id = blockIdx.x * 256 + threadIdx.x;   // 0..262143
  int b = id >> 12, w = id & 4095;
  const float* s = out + SPIKES_OFF + (size_t)b * T * WID + w;
  float acc = 0.f;
  for (int t = 0; t < T; ++t) acc = fmaf(s[(size_t)t * WID], dec[t], acc);
  wt[id] = acc;
}

// logits[b,c] = sum_w weighted[b,w]*W2q[c,w] + b2[c]
__global__ void logits_kernel(const float* __restrict__ wt,
                              const float* __restrict__ w2,
                              const float* __restrict__ b2,
                              float* __restrict__ out) {
  int id = blockIdx.x * 256 + threadIdx.x;
  if (id >= B * CLS) return;
  int b = id / CLS, c = id % CLS;
  const float* wr = wt + (size_t)b * WID;
  const float* w2r = w2 + (size_t)c * WID;
  float acc = 0.f;
  for (int w = 0; w < WID; ++w) acc = fmaf(wr[w], w2r[w], acc);
  out[LOGITS_OFF + id] = acc + b2[c];
}

extern "C" void kernel_launch(void* const* d_in, const int* in_sizes, int n_in,
                              void* d_out, int out_size, void* d_ws, size_t ws_size,
                              hipStream_t stream) {
  (void)in_sizes; (void)n_in; (void)out_size; (void)ws_size;
  const float* x         = (const float*)d_in[0];
  const float* latent    = (const float*)d_in[1];
  const float* spatial_W = (const float*)d_in[2];
  const float* spatial_b = (const float*)d_in[3];
  const float* conv_W    = (const float*)d_in[4];
  const float* conv_b    = (const float*)d_in[5];
  const float* fc1_W     = (const float*)d_in[6];
  const float* fc1_b     = (const float*)d_in[7];
  const float* fc2_W     = (const float*)d_in[8];
  const float* fc2_b     = (const float*)d_in[9];
  const float* gain      = (const float*)d_in[10];
  float* out = (float*)d_out;
  uint32_t* wsu = (uint32_t*)d_ws;
  float* wsf = (float*)d_ws;

  // Host-side RNG chain (partitionable split, foldlike):
  // rng0=(0,42); rng,subkey = split(rng0): subkey = full pair of threefry(rng0,(0,1)).
  uint32_t sk0, sk1;
  threefry2x32(0u, 42u, 0u, 1u, sk0, sk1);

  hipMemsetAsync(wsu + WS_SLOTS, 0, 3 * sizeof(uint32_t), stream);
  absmax_kernel<<<64, 256, 0, stream>>>(spatial_W, RED * IN_F, wsu + WS_SLOTS + 0);
  absmax_kernel<<<256, 256, 0, stream>>>(fc1_W, WID * RED, wsu + WS_SLOTS + 1);
  absmax_kernel<<<32, 256, 0, stream>>>(fc2_W, CLS * WID, wsu + WS_SLOTS + 2);
  quant_kernel<<<(RED * IN_F + 255) / 256, 256, 0, stream>>>(spatial_W, wsf + WS_WSQ, RED * IN_F, wsu + WS_SLOTS + 0);
  quant_kernel<<<(WID * RED + 255) / 256, 256, 0, stream>>>(fc1_W, wsf + WS_W1Q, WID * RED, wsu + WS_SLOTS + 1);
  quant_kernel<<<(CLS * WID + 255) / 256, 256, 0, stream>>>(fc2_W, wsf + WS_W2Q, CLS * WID, wsu + WS_SLOTS + 2);
  spatial_kernel<<<BT / 8, 256, 0, stream>>>(x, wsf + WS_WSQ, spatial_b, wsf + WS_XP);
  conv_kernel<<<B * 10, 256, 0, stream>>>(wsf + WS_XP, conv_W, conv_b, wsf + WS_CO);
  fc1_kernel<<<(BT / 8) * 16, 256, 0, stream>>>(wsf + WS_CO, wsf + WS_W1Q, fc1_b, latent, gain, out);
  spike_kernel<<<NELEM / 256, 256, 0, stream>>>(out, sk0, sk1);
  weighted_kernel<<<(B * WID) / 256, 256, 0, stream>>>(out, wsf + WS_WEIGHTED);
  logits_kernel<<<(B * CLS + 255) / 256, 256, 0, stream>>>(wsf + WS_WEIGHTED, wsf + WS_W2Q, fc2_b, out);
}

// Round 4
// 1215.482 us; speedup vs baseline: 1.1535x; 1.1535x over previous
//
#include <hip/hip_runtime.h>
#include <stdint.h>

#define B 64
#define T 100
#define IN_F 700
#define RED 256
#define WID 4096
#define CLS 20
#define BT (B*T)                   // 6400
#define NELEM (BT*WID)             // 26,214,400
#define LOGITS_OFF 0
#define SPIKES_OFF (B*CLS)         // 1280
#define DRIVE_OFF (SPIKES_OFF + NELEM)

// ---- ws layout (floats) ----
#define WS_SLOTS 0                            // 3 u32
#define WS_W2Q 16                             // 20*4096
#define WS_XP  (WS_W2Q + CLS*WID)             // 6400*256
#define WS_CO  (WS_XP + BT*RED)               // 6400*256
#define WS_WEIGHTED (WS_CO + BT*RED)          // 64*4096

// ---- scratch inside d_out's spikes region (consumed before spikes written) ----
#define SC_WST 0                              // 700*256   transposed q4(spatial_W)
#define SC_W1T (SC_WST + IN_F*RED)            // 256*4096  transposed q4(fc1_W)
#define SC_CWT (SC_W1T + RED*WID)             // 1280*256  conv_W as [h][ic][o]
#define SC_IM2 (SC_CWT + 1280*256)            // 6400*1280 im2col of xp

__host__ __device__ __forceinline__ uint32_t rotl32(uint32_t v, int r) {
  return (v << r) | (v >> (32 - r));
}

// JAX threefry2x32 (20 rounds), bit-exact.
__host__ __device__ __forceinline__ void threefry2x32(uint32_t k0, uint32_t k1,
                                                      uint32_t x0, uint32_t x1,
                                                      uint32_t& o0, uint32_t& o1) {
  uint32_t k2 = k0 ^ k1 ^ 0x1BD11BDAu;
  x0 += k0; x1 += k1;
#define TF_R(r) { x0 += x1; x1 = rotl32(x1, (r)); x1 ^= x0; }
  TF_R(13) TF_R(15) TF_R(26) TF_R(6)
  x0 += k1; x1 += k2 + 1u;
  TF_R(17) TF_R(29) TF_R(16) TF_R(24)
  x0 += k2; x1 += k0 + 2u;
  TF_R(13) TF_R(15) TF_R(26) TF_R(6)
  x0 += k0; x1 += k1 + 3u;
  TF_R(17) TF_R(29) TF_R(16) TF_R(24)
  x0 += k1; x1 += k2 + 4u;
  TF_R(13) TF_R(15) TF_R(26) TF_R(6)
  x0 += k2; x1 += k0 + 5u;
#undef TF_R
  o0 = x0; o1 = x1;
}

__global__ void absmax_kernel(const float* __restrict__ w, int n, uint32_t* slot) {
  __shared__ uint32_t sm[256];
  uint32_t m = 0u;
  for (int i = blockIdx.x * 256 + threadIdx.x; i < n; i += gridDim.x * 256)
    m = max(m, __float_as_uint(fabsf(w[i])));
  sm[threadIdx.x] = m;
  __syncthreads();
  for (int s = 128; s > 0; s >>= 1) {
    if (threadIdx.x < s) sm[threadIdx.x] = max(sm[threadIdx.x], sm[threadIdx.x + s]);
    __syncthreads();
  }
  if (threadIdx.x == 0) atomicMax(slot, sm[0]);
}

// quantize (identical float ops as before) + transpose to [k][n]
__global__ void quant_t_kernel(const float* __restrict__ w, float* __restrict__ qT,
                               int Nn, int Kk, const uint32_t* __restrict__ slot) {
  float s = fmaxf(__uint_as_float(*slot) / 7.0f, 1e-8f);
  int id = blockIdx.x * 256 + threadIdx.x;
  if (id < Nn * Kk) {
    int n = id / Kk, k = id - n * Kk;
    qT[(size_t)k * Nn + n] = rintf(w[id] / s) * s;
  }
}

__global__ void quant_kernel(const float* __restrict__ w, float* __restrict__ q,
                             int n, const uint32_t* __restrict__ slot) {
  float s = fmaxf(__uint_as_float(*slot) / 7.0f, 1e-8f);
  int i = blockIdx.x * 256 + threadIdx.x;
  if (i < n) q[i] = rintf(w[i] / s) * s;
}

// conv_W [o][ic][h] -> [h*256+ic][o]  (k-major with h outer, ic inner: matches
// the verified accumulation order)
__global__ void convw_t_kernel(const float* __restrict__ w, float* __restrict__ wt) {
  int id = blockIdx.x * 256 + threadIdx.x;   // < 256*1280
  if (id < 256 * 1280) {
    int o = id / 1280, r = id - o * 1280;
    int ic = r / 5, h = r - ic * 5;
    wt[(size_t)((h << 8) + ic) * 256 + o] = w[id];
  }
}

// im2col: A2[bt][h*256+ic] = xp[b][t+h-2][ic] (zero pad), k ascending = (h,ic)
__global__ void im2col_kernel(const float* __restrict__ xp, float* __restrict__ A2) {
  int id = blockIdx.x * 256 + threadIdx.x;   // < 6400*1280
  int bt = id / 1280;
  int k = id - bt * 1280;
  int h = k >> 8, ic = k & 255;
  int b = bt / T, t = bt - b * T;
  int tt = t + h - 2;
  float v = 0.f;
  if (tt >= 0 && tt < T) v = xp[((size_t)(b * T + tt)) * RED + ic];
  A2[id] = v;
}

// Tiled GEMM: C[m][n] = epi( sum_k A[m][k]*Bt[k][n] + bias[n] ).
// Per-element accumulation is fmaf over k ascending from 0 -> bit-identical
// to the verified round-3 kernels. EPI: 0 = relu, 1 = softplus*latent*|gain|.
template<int MT, int NT, int EPI>
__global__ __launch_bounds__(256, 4)
void gemm_kernel(const float* __restrict__ A, const float* __restrict__ Bt,
                 const float* __restrict__ bias, const float* __restrict__ latent,
                 const float* __restrict__ gain, float* __restrict__ C,
                 int M, int N, int K) {
  constexpr int TM = MT / 16, TN = NT / 16;
  constexpr int ASR = MT + 4, BSR = NT + 4;
  __shared__ float As[32 * ASR];
  __shared__ float Bs[32 * BSR];
  int tid = threadIdx.x;
  int tx = tid & 15, ty = tid >> 4;
  int m0 = blockIdx.x * MT, n0 = blockIdx.y * NT;
  float acc[TM * TN];
#pragma unroll
  for (int i = 0; i < TM * TN; ++i) acc[i] = 0.f;

  for (int kt = 0; kt < K; kt += 32) {
    int klen = K - kt; if (klen > 32) klen = 32;
    // stage A (transposed to k-major): MT*32 elems, coalesced along k
#pragma unroll
    for (int rep = 0; rep < MT / 8; ++rep) {
      int e = rep * 256 + tid;
      int kk = e & 31, m = e >> 5;
      float v = 0.f;
      if (kk < klen) v = A[(size_t)(m0 + m) * K + kt + kk];
      As[kk * ASR + m] = v;
    }
    // stage B: 32*NT elems, coalesced along n
#pragma unroll
    for (int rep = 0; rep < NT / 8; ++rep) {
      int e = rep * 256 + tid;
      int kk = e / NT, n = e % NT;
      float v = 0.f;
      if (kk < klen) v = Bt[(size_t)(kt + kk) * N + n0 + n];
      Bs[kk * BSR + n] = v;
    }
    __syncthreads();
    if (klen == 32) {
#pragma unroll
      for (int kk = 0; kk < 32; ++kk) {
        float a[TM], b[TN];
#pragma unroll
        for (int i = 0; i < TM; ++i) a[i] = As[kk * ASR + ty * TM + i];
#pragma unroll
        for (int d = 0; d < TN; ++d) b[d] = Bs[kk * BSR + tx * TN + d];
#pragma unroll
        for (int j = 0; j < TM; ++j)
#pragma unroll
          for (int d = 0; d < TN; ++d)
            acc[j * TN + d] = fmaf(a[j], b[d], acc[j * TN + d]);
      }
    } else {
      for (int kk = 0; kk < klen; ++kk) {
        float a[TM], b[TN];
#pragma unroll
        for (int i = 0; i < TM; ++i) a[i] = As[kk * ASR + ty * TM + i];
#pragma unroll
        for (int d = 0; d < TN; ++d) b[d] = Bs[kk * BSR + tx * TN + d];
#pragma unroll
        for (int j = 0; j < TM; ++j)
#pragma unroll
          for (int d = 0; d < TN; ++d)
            acc[j * TN + d] = fmaf(a[j], b[d], acc[j * TN + d]);
      }
    }
    __syncthreads();
  }

  float bv[TN];
#pragma unroll
  for (int d = 0; d < TN; ++d) bv[d] = bias[n0 + tx * TN + d];
  if (EPI == 0) {
#pragma unroll
    for (int j = 0; j < TM; ++j) {
      int m = m0 + ty * TM + j;
#pragma unroll
      for (int d = 0; d < TN; ++d)
        C[(size_t)m * N + n0 + tx * TN + d] = fmaxf(acc[j * TN + d] + bv[d], 0.0f);
    }
  } else {
    float g = fabsf(gain[0]);
#pragma unroll
    for (int j = 0; j < TM; ++j) {
      int bt = m0 + ty * TM + j;
      float lat = latent[bt % T];
#pragma unroll
      for (int d = 0; d < TN; ++d) {
        float v = acc[j * TN + d] + bv[d];
        float e = expf(-fabsf(v));
        float l = log1pf(e);
        float sp = fmaxf(v, 0.0f) + l;
        C[(size_t)bt * N + n0 + tx * TN + d] = (sp * lat) * g;
      }
    }
  }
}

// Fused spike sampling + decay-weighted reduction.
// spikes = [lam>0 && log(u1) > -lam]; u1 = partitionable threefry XOR-fold.
__global__ __launch_bounds__(256) void spike_weighted_kernel(float* __restrict__ out,
                                                             float* __restrict__ wt,
                                                             uint32_t k0, uint32_t k1) {
  __shared__ float dec[128];
  int tid = threadIdx.x;
  if (tid < T) {
    float step = 2.0f / 99.0f;
    float a = step * (float)tid;
    dec[tid] = expf(a - 2.0f);
  }
  __syncthreads();
  int b = blockIdx.x >> 4;
  int w = ((blockIdx.x & 15) << 8) + tid;
  float acc = 0.f;
  for (int t = 0; t < T; ++t) {
    uint32_t p = (uint32_t)((b * T + t) * WID + w);
    float lam = out[DRIVE_OFF + p];
    uint32_t y0, y1;
    threefry2x32(k0, k1, 0u, p, y0, y1);
    uint32_t bits = y0 ^ y1;
    float u = __uint_as_float((bits >> 9) | 0x3f800000u) - 1.0f;
    float s = (lam > 0.0f && logf(u) > -lam) ? 1.0f : 0.0f;
    out[SPIKES_OFF + p] = s;
    acc = fmaf(s, dec[t], acc);
  }
  wt[b * WID + w] = acc;
}

// logits[b,c] = sum_w weighted[b,w]*W2q[c,w] + b2[c]  (block tree-reduce; f32
// order differs from np but threshold here is ~0.85 vs ~1e-4 error)
__global__ void logits_kernel(const float* __restrict__ wt,
                              const float* __restrict__ w2,
                              const float* __restrict__ b2,
                              float* __restrict__ out) {
  __shared__ float sm[256];
  int b = blockIdx.x / CLS, c = blockIdx.x - b * CLS;
  const float* wr = wt + (size_t)b * WID;
  const float* w2r = w2 + (size_t)c * WID;
  float p = 0.f;
  for (int w = threadIdx.x; w < WID; w += 256) p = fmaf(wr[w], w2r[w], p);
  sm[threadIdx.x] = p;
  __syncthreads();
  for (int s = 128; s > 0; s >>= 1) {
    if (threadIdx.x < s) sm[threadIdx.x] += sm[threadIdx.x + s];
    __syncthreads();
  }
  if (threadIdx.x == 0) out[LOGITS_OFF + blockIdx.x] = sm[0] + b2[c];
}

extern "C" void kernel_launch(void* const* d_in, const int* in_sizes, int n_in,
                              void* d_out, int out_size, void* d_ws, size_t ws_size,
                              hipStream_t stream) {
  (void)in_sizes; (void)n_in; (void)out_size; (void)ws_size;
  const float* x         = (const float*)d_in[0];
  const float* latent    = (const float*)d_in[1];
  const float* spatial_W = (const float*)d_in[2];
  const float* spatial_b = (const float*)d_in[3];
  const float* conv_W    = (const float*)d_in[4];
  const float* conv_b    = (const float*)d_in[5];
  const float* fc1_W     = (const float*)d_in[6];
  const float* fc1_b     = (const float*)d_in[7];
  const float* fc2_W     = (const float*)d_in[8];
  const float* fc2_b     = (const float*)d_in[9];
  const float* gain      = (const float*)d_in[10];
  float* out = (float*)d_out;
  uint32_t* wsu = (uint32_t*)d_ws;
  float* wsf = (float*)d_ws;
  float* S = out + SPIKES_OFF;   // scratch in the not-yet-written spikes region

  // rng chain (partitionable split): subkey = full pair of threefry(rng0,(0,1))
  uint32_t sk0, sk1;
  threefry2x32(0u, 42u, 0u, 1u, sk0, sk1);

  hipMemsetAsync(wsu + WS_SLOTS, 0, 3 * sizeof(uint32_t), stream);
  absmax_kernel<<<64, 256, 0, stream>>>(spatial_W, RED * IN_F, wsu + WS_SLOTS + 0);
  absmax_kernel<<<256, 256, 0, stream>>>(fc1_W, WID * RED, wsu + WS_SLOTS + 1);
  absmax_kernel<<<32, 256, 0, stream>>>(fc2_W, CLS * WID, wsu + WS_SLOTS + 2);

  quant_t_kernel<<<700, 256, 0, stream>>>(spatial_W, S + SC_WST, RED, IN_F, wsu + WS_SLOTS + 0);
  quant_t_kernel<<<4096, 256, 0, stream>>>(fc1_W, S + SC_W1T, WID, RED, wsu + WS_SLOTS + 1);
  quant_kernel<<<320, 256, 0, stream>>>(fc2_W, wsf + WS_W2Q, CLS * WID, wsu + WS_SLOTS + 2);
  convw_t_kernel<<<1280, 256, 0, stream>>>(conv_W, S + SC_CWT);

  // spatial: xp = relu(x @ WsqT + b)   M=6400 N=256 K=700
  gemm_kernel<64, 64, 0><<<dim3(100, 4), 256, 0, stream>>>(
      x, S + SC_WST, spatial_b, nullptr, nullptr, wsf + WS_XP, BT, RED, IN_F);

  im2col_kernel<<<32000, 256, 0, stream>>>(wsf + WS_XP, S + SC_IM2);

  // conv: co = relu(im2col @ cwt + cb)  M=6400 N=256 K=1280
  gemm_kernel<64, 64, 0><<<dim3(100, 4), 256, 0, stream>>>(
      S + SC_IM2, S + SC_CWT, conv_b, nullptr, nullptr, wsf + WS_CO, BT, RED, 1280);

  // fc1: drive = softplus(co @ W1qT + b)*latent*|g|  M=6400 N=4096 K=256
  gemm_kernel<128, 64, 1><<<dim3(50, 64), 256, 0, stream>>>(
      wsf + WS_CO, S + SC_W1T, fc1_b, latent, gain, out + DRIVE_OFF, BT, WID, RED);

  spike_weighted_kernel<<<B * 16, 256, 0, stream>>>(out, wsf + WS_WEIGHTED, sk0, sk1);

  logits_kernel<<<B * CLS, 256, 0, stream>>>(wsf + WS_WEIGHTED, wsf + WS_W2Q, fc2_b, out);
}